// Round 14
// baseline (131.716 us; speedup 1.0000x reference)
//
#include <hip/hip_runtime.h>
#include <math.h>

#define B    64
#define NPG  1024
#define KEIG 32
#define DIN  512
#define DOUT 512
#define NPART 8   // k2 n-chunk partials

typedef float  f32x4  __attribute__((ext_vector_type(4)));
typedef short  bf16x8 __attribute__((ext_vector_type(8)));

__device__ __forceinline__ unsigned short f2bf(float x) {
    union { float f; unsigned int u; } v; v.f = x;
    unsigned int r = v.u + 0x7FFFu + ((v.u >> 16) & 1u);   // round-nearest-even
    return (unsigned short)(r >> 16);
}

__device__ __forceinline__ float rsum32(float v) {
    v += __shfl_xor(v, 1, 32);
    v += __shfl_xor(v, 2, 32);
    v += __shfl_xor(v, 4, 32);
    v += __shfl_xor(v, 8, 32);
    v += __shfl_xor(v, 16, 32);
    return v;
}
__device__ __forceinline__ float rmax32(float v) {
    v = fmaxf(v, __shfl_xor(v, 1, 32));
    v = fmaxf(v, __shfl_xor(v, 2, 32));
    v = fmaxf(v, __shfl_xor(v, 4, 32));
    v = fmaxf(v, __shfl_xor(v, 8, 32));
    v = fmaxf(v, __shfl_xor(v, 16, 32));
    return v;
}

// ---------------------------------------------------------------------------
// Kernel 1: feature-parallel encoder + MHSA + filter head. (~8us, unchanged)
// ---------------------------------------------------------------------------
__global__ __launch_bounds__(1024) void k1_filters(
    const float* __restrict__ eigenvalues,
    const float* __restrict__ W1,  const float* __restrict__ b1,
    const float* __restrict__ g1,  const float* __restrict__ be1,
    const float* __restrict__ W2,  const float* __restrict__ b2,
    const float* __restrict__ g2,  const float* __restrict__ be2,
    const float* __restrict__ Wqkv,const float* __restrict__ bqkv,
    const float* __restrict__ Wo,  const float* __restrict__ bo,
    const float* __restrict__ Wf1, const float* __restrict__ bf1,
    const float* __restrict__ Wf2, const float* __restrict__ bf2,
    float* __restrict__ filters)
{
    __shared__ float wts[224][33];
    __shared__ float hA[KEIG][33];
    __shared__ float hB[KEIG][33];
    __shared__ float qkv[KEIG][97];
    __shared__ float attn[4 * 1064];

    const int t = threadIdx.x;
    const int k = t >> 5;
    const int j = t & 31;
    const int b = blockIdx.x;

    {
        const int row = t >> 5, i = t & 31;
        wts[row][i]       = W2[t];
        wts[32 + row][i]  = Wqkv[t];
        wts[64 + row][i]  = Wqkv[1024 + t];
        wts[96 + row][i]  = Wqkv[2048 + t];
        wts[128 + row][i] = Wo[t];
        wts[160 + row][i] = Wf1[t];
        wts[192 + row][i] = Wf1[1024 + t];
    }

    const float ev = eigenvalues[b * KEIG + k];
    float h1 = ev * W1[j] + b1[j];
    {
        float m = rsum32(h1) * (1.f / 32.f);
        float d = h1 - m;
        float q = rsum32(d * d);
        float r = rsqrtf(q * (1.f / 32.f) + 1e-5f);
        h1 = fmaxf(d * r * g1[j] + be1[j], 0.f);
    }
    hA[k][j] = h1;
    __syncthreads();

    {
        float a = b2[j];
        #pragma unroll
        for (int i = 0; i < 32; ++i) a += hA[k][i] * wts[j][i];
        float m = rsum32(a) * (1.f / 32.f);
        float d = a - m;
        float q = rsum32(d * d);
        float r = rsqrtf(q * (1.f / 32.f) + 1e-5f);
        hB[k][j] = d * r * g2[j] + be2[j];
    }
    __syncthreads();

    {
        float aq = bqkv[j], ak = bqkv[32 + j], av = bqkv[64 + j];
        #pragma unroll
        for (int i = 0; i < 32; ++i) {
            float hv = hB[k][i];
            aq += hv * wts[32 + j][i];
            ak += hv * wts[64 + j][i];
            av += hv * wts[96 + j][i];
        }
        qkv[k][j]      = aq;
        qkv[k][32 + j] = ak;
        qkv[k][64 + j] = av;
    }
    __syncthreads();

    {
        const float inv = 0.35355339059327373f;
        float sc[4];
        #pragma unroll
        for (int hh = 0; hh < 4; ++hh) {
            float s = 0.f;
            #pragma unroll
            for (int d2 = 0; d2 < 8; ++d2)
                s += qkv[k][hh * 8 + d2] * qkv[j][32 + hh * 8 + d2];
            sc[hh] = s * inv;
        }
        #pragma unroll
        for (int hh = 0; hh < 4; ++hh) {
            float mx  = rmax32(sc[hh]);
            float e   = __expf(sc[hh] - mx);
            float den = rsum32(e);
            attn[hh * 1064 + k * 33 + j] = e / den;
        }
    }
    __syncthreads();

    {
        const int hh = j >> 3;
        float c = 0.f;
        #pragma unroll
        for (int k2 = 0; k2 < 32; ++k2)
            c += attn[hh * 1064 + k * 33 + k2] * qkv[k2][64 + j];
        hA[k][j] = c;
    }
    __syncthreads();

    {
        float o = bo[j];
        #pragma unroll
        for (int i = 0; i < 32; ++i) o += hA[k][i] * wts[128 + j][i];
        hB[k][j] = o;
    }
    __syncthreads();

    {
        float r0 = bf1[j], r1 = bf1[32 + j];
        #pragma unroll
        for (int i = 0; i < 32; ++i) {
            float ov = hB[k][i];
            r0 += ov * wts[160 + j][i];
            r1 += ov * wts[192 + j][i];
        }
        float fp = fmaxf(r0, 0.f) * Wf2[j] + fmaxf(r1, 0.f) * Wf2[32 + j];
        fp = rsum32(fp);
        if (j == 0) filters[b * KEIG + k] = tanhf(fp + bf2[0]);
    }
}

// ---------------------------------------------------------------------------
// Kernel 2: xfp[nc][b][k][d] = sum_{n in 128-row chunk} vg[n,k]*x[n,d]
// (~30us; near its 176MB traffic roofline, unchanged)
// ---------------------------------------------------------------------------
__global__ __launch_bounds__(256) void k2_xfreq_partial(
    const float* __restrict__ x, const float* __restrict__ eigvec,
    float* __restrict__ xfp)
{
    __shared__ float vtile[128][32];
    const int t  = threadIdx.x;
    const int b  = blockIdx.x >> 4;
    const int nc = (blockIdx.x >> 1) & 7;
    const int dh = blockIdx.x & 1;
    const int kq = t >> 6;
    const int ds = t & 63;
    const int d  = dh * 256 + ds * 4;
    const int n0 = nc * 128;

    const float* vb = eigvec + ((size_t)(b * NPG + n0)) * KEIG;
    #pragma unroll
    for (int e = 0; e < 16; ++e) {
        int idx = t + e * 256;
        ((float*)vtile)[idx] = vb[idx];
    }
    __syncthreads();

    float4 acc[8];
    #pragma unroll
    for (int i = 0; i < 8; ++i) acc[i] = make_float4(0.f, 0.f, 0.f, 0.f);

    const float* xb = x + ((size_t)(b * NPG + n0)) * DIN + d;
    #pragma unroll 4
    for (int n = 0; n < 128; ++n) {
        float4 xv = *(const float4*)(xb + (size_t)n * DIN);
        const float4* vp = (const float4*)&vtile[n][kq * 8];
        float4 v0 = vp[0], v1 = vp[1];
        acc[0].x += v0.x * xv.x; acc[0].y += v0.x * xv.y; acc[0].z += v0.x * xv.z; acc[0].w += v0.x * xv.w;
        acc[1].x += v0.y * xv.x; acc[1].y += v0.y * xv.y; acc[1].z += v0.y * xv.z; acc[1].w += v0.y * xv.w;
        acc[2].x += v0.z * xv.x; acc[2].y += v0.z * xv.y; acc[2].z += v0.z * xv.z; acc[2].w += v0.z * xv.w;
        acc[3].x += v0.w * xv.x; acc[3].y += v0.w * xv.y; acc[3].z += v0.w * xv.z; acc[3].w += v0.w * xv.w;
        acc[4].x += v1.x * xv.x; acc[4].y += v1.x * xv.y; acc[4].z += v1.x * xv.z; acc[4].w += v1.x * xv.w;
        acc[5].x += v1.y * xv.x; acc[5].y += v1.y * xv.y; acc[5].z += v1.y * xv.z; acc[5].w += v1.y * xv.w;
        acc[6].x += v1.z * xv.x; acc[6].y += v1.z * xv.y; acc[6].z += v1.z * xv.z; acc[6].w += v1.z * xv.w;
        acc[7].x += v1.w * xv.x; acc[7].y += v1.w * xv.y; acc[7].z += v1.w * xv.z; acc[7].w += v1.w * xv.w;
    }

    #pragma unroll
    for (int kk = 0; kk < 8; ++kk) {
        int kg = kq * 8 + kk;
        *(float4*)(xfp + (((size_t)nc * B + b) * KEIG + kg) * DIN + d) = acc[kk];
    }
}

// ---------------------------------------------------------------------------
// Kernel 2b: F[m][d] = filters[m] * sum_nc xfp[nc][m][d].  (~7us, unchanged)
// ---------------------------------------------------------------------------
__global__ __launch_bounds__(256) void k2b_combine(
    const float* __restrict__ xfp, const float* __restrict__ filters,
    float* __restrict__ F)
{
    const int t = threadIdx.x;
    const int m = blockIdx.x * 2 + (t >> 7);
    const int dp = (t & 127) * 4;

    const float* base = xfp + (size_t)m * DIN + dp;
    float4 s = *(const float4*)base;
    #pragma unroll
    for (int q = 1; q < NPART; ++q) {
        float4 sq = *(const float4*)(base + (size_t)q * (B * KEIG * DIN));
        s.x += sq.x; s.y += sq.y; s.z += sq.z; s.w += sq.w;
    }
    const float f = filters[m];
    float4 o = make_float4(s.x * f, s.y * f, s.z * f, s.w * f);
    *(float4*)(F + (size_t)m * DIN + dp) = o;
}

// ---------------------------------------------------------------------------
// Kernel 3: GEMM G[m][o] = sum_d F[m][d]*Wp[o][d], now emitting G transposed
// in bf16: Gt[b][o][k] (2 MB). 2-byte scatter epilogue (small output). ~15us.
// ---------------------------------------------------------------------------
__global__ __launch_bounds__(256) void k3_G(
    const float* __restrict__ F, const float* __restrict__ Wp,
    unsigned short* __restrict__ Gt)
{
    __shared__ float a_lds[64][65];
    __shared__ float b_lds[64][65];

    const int t   = threadIdx.x;
    const int mt  = blockIdx.x >> 3;
    const int ot  = blockIdx.x & 7;
    const int m0  = mt * 64;
    const int o0  = ot * 64;
    const int tr  = t >> 4;
    const int tc  = t & 15;
    const int col4 = tc * 4;

    float acc[4][4] = {{0.f}};

    for (int d0 = 0; d0 < DIN; d0 += 64) {
        __syncthreads();
        #pragma unroll
        for (int p = 0; p < 4; ++p) {
            int r = p * 16 + tr;
            float4 s = *(const float4*)(F + (size_t)(m0 + r) * DIN + d0 + col4);
            a_lds[r][col4 + 0] = s.x;
            a_lds[r][col4 + 1] = s.y;
            a_lds[r][col4 + 2] = s.z;
            a_lds[r][col4 + 3] = s.w;
        }
        #pragma unroll
        for (int p = 0; p < 4; ++p) {
            int r = p * 16 + tr;
            float4 w = *(const float4*)(Wp + (size_t)(o0 + r) * DIN + d0 + col4);
            b_lds[r][col4 + 0] = w.x;
            b_lds[r][col4 + 1] = w.y;
            b_lds[r][col4 + 2] = w.z;
            b_lds[r][col4 + 3] = w.w;
        }
        __syncthreads();
        #pragma unroll 4
        for (int dd = 0; dd < 64; ++dd) {
            float a0 = a_lds[tr * 4 + 0][dd];
            float a1 = a_lds[tr * 4 + 1][dd];
            float a2 = a_lds[tr * 4 + 2][dd];
            float a3 = a_lds[tr * 4 + 3][dd];
            float b0 = b_lds[tc * 4 + 0][dd];
            float b1 = b_lds[tc * 4 + 1][dd];
            float b2 = b_lds[tc * 4 + 2][dd];
            float b3 = b_lds[tc * 4 + 3][dd];
            acc[0][0] += a0 * b0; acc[0][1] += a0 * b1; acc[0][2] += a0 * b2; acc[0][3] += a0 * b3;
            acc[1][0] += a1 * b0; acc[1][1] += a1 * b1; acc[1][2] += a1 * b2; acc[1][3] += a1 * b3;
            acc[2][0] += a2 * b0; acc[2][1] += a2 * b1; acc[2][2] += a2 * b2; acc[2][3] += a2 * b3;
            acc[3][0] += a3 * b0; acc[3][1] += a3 * b1; acc[3][2] += a3 * b2; acc[3][3] += a3 * b3;
        }
    }
    // epilogue: Gt[b][o][k] = bf16(acc), b = m>>5, k = m&31, o = o0+tc*4+j
    #pragma unroll
    for (int i = 0; i < 4; ++i) {
        int m  = m0 + tr * 4 + i;
        int bb = m >> 5, kk = m & 31;
        #pragma unroll
        for (int j = 0; j < 4; ++j) {
            int o = o0 + tc * 4 + j;
            Gt[((size_t)bb * DOUT + o) * KEIG + kk] = f2bf(acc[i][j]);
        }
    }
}

// ---------------------------------------------------------------------------
// Kernel 4 (v11 — MFMA): out[n,:] = LN( vg[n,:] @ G[b] + bp ) * gp + bep
// The K=32 matmul finally goes on the matrix cores (Common-mistake #10: all
// prior variants ran 4096 scalar FMAs/thread on the VALU; 8 memory-side
// probes were neutral because the binding cost was the instruction stream).
// grid = B*16 = 1024 blocks, 256 thr = 4 waves x 16 rows x 512 cols.
// Per wave: ONE A-fragment (vg rows, bf16) reused over 32 col-tiles; per
// tile 1 ds_read_b128 B-frag (Gt[col][k] layout, 40-ushort row pad -> 2-way
// banks = free) + 1 mfma_f32_16x16x32_bf16. fp32 accumulate; bias+LN fp32.
// C/D layout (m89-verified): col=lane&15, row=(lane>>4)*4+reg -> LN row
// reduce = width-16 shfl butterfly within lane groups. ~700 instr/thread
// vs ~5000 before; kernel becomes store-bound (~21us floor for 134 MB).
// ---------------------------------------------------------------------------
__global__ __launch_bounds__(256, 1) void k4_out(
    const float* __restrict__ eigvec, const unsigned short* __restrict__ Gt,
    const float* __restrict__ bp, const float* __restrict__ gp,
    const float* __restrict__ bep, float* __restrict__ out)
{
    __shared__ unsigned short gt_lds[512][40];   // 40 KB, pad 40 -> 2-way banks
    __shared__ float prm[3 * 512];               // bp | gp | bep

    const int t  = threadIdx.x;
    const int b  = blockIdx.x >> 4;
    const int n0 = (blockIdx.x & 15) * 64;

    // stage Gt[b] (32 KB, coalesced 16B chunks)
    {
        const unsigned short* src = Gt + (size_t)b * (DOUT * KEIG);
        #pragma unroll
        for (int e = 0; e < 8; ++e) {
            int c = t + e * 256;            // chunk 0..2047
            int row = c >> 2, part = c & 3;
            bf16x8 v = *(const bf16x8*)(src + c * 8);
            *(bf16x8*)&gt_lds[row][part * 8] = v;
        }
    }
    #pragma unroll
    for (int e = 0; e < 6; ++e) {
        int idx = t + e * 256;
        prm[idx] = (idx < 512) ? bp[idx]
                 : (idx < 1024) ? gp[idx - 512] : bep[idx - 1024];
    }
    __syncthreads();

    const int w  = t >> 6;      // wave 0..3 -> rows w*16..w*16+15
    const int l  = t & 63;
    const int cl = l & 15;      // col within 16-tile / A row lane
    const int g  = l >> 4;      // lane group 0..3
    const int kb = g * 8;       // k-slice for A/B fragments

    // A fragment: vg[n0+w*16+cl][kb..kb+7] -> 8 bf16 (RNE)
    bf16x8 afrag;
    {
        const float* ar = eigvec + ((size_t)(b * NPG + n0 + w * 16 + cl)) * KEIG + kb;
        float4 a0 = *(const float4*)(ar);
        float4 a1 = *(const float4*)(ar + 4);
        afrag[0] = (short)f2bf(a0.x); afrag[1] = (short)f2bf(a0.y);
        afrag[2] = (short)f2bf(a0.z); afrag[3] = (short)f2bf(a0.w);
        afrag[4] = (short)f2bf(a1.x); afrag[5] = (short)f2bf(a1.y);
        afrag[6] = (short)f2bf(a1.z); afrag[7] = (short)f2bf(a1.w);
    }

    f32x4 acc[32];
    #pragma unroll
    for (int ct = 0; ct < 32; ++ct) acc[ct] = (f32x4){0.f, 0.f, 0.f, 0.f};

    #pragma unroll
    for (int ct = 0; ct < 32; ++ct) {
        bf16x8 bfrag = *(const bf16x8*)&gt_lds[ct * 16 + cl][kb];
        acc[ct] = __builtin_amdgcn_mfma_f32_16x16x32_bf16(afrag, bfrag, acc[ct], 0, 0, 0);
    }

    // LN stats: lane holds rows g*4+j (j=0..3), cols {ct*16+cl}
    float s[4] = {0.f, 0.f, 0.f, 0.f}, q[4] = {0.f, 0.f, 0.f, 0.f};
    #pragma unroll
    for (int ct = 0; ct < 32; ++ct) {
        float bpc = prm[ct * 16 + cl];
        #pragma unroll
        for (int j = 0; j < 4; ++j) {
            float v = acc[ct][j] + bpc;
            s[j] += v; q[j] += v * v;
        }
    }
    #pragma unroll
    for (int off = 1; off < 16; off <<= 1) {
        #pragma unroll
        for (int j = 0; j < 4; ++j) {
            s[j] += __shfl_xor(s[j], off, 16);
            q[j] += __shfl_xor(q[j], off, 16);
        }
    }
    float mh[4], rs[4];
    #pragma unroll
    for (int j = 0; j < 4; ++j) {
        mh[j] = s[j] * (1.f / 512.f);
        rs[j] = rsqrtf(q[j] * (1.f / 512.f) - mh[j] * mh[j] + 1e-5f);
    }

    // store: 4 rows x 32 col-tiles, 64B-coalesced per 16-lane group
    const size_t rowbase = (size_t)b * NPG + n0 + w * 16 + g * 4;
    #pragma unroll
    for (int ct = 0; ct < 32; ++ct) {
        int col = ct * 16 + cl;
        float bpc = prm[col];
        float gpc = prm[512 + col];
        float bec = prm[1024 + col];
        #pragma unroll
        for (int j = 0; j < 4; ++j) {
            float v = (acc[ct][j] + bpc - mh[j]) * rs[j] * gpc + bec;
            __builtin_nontemporal_store(v, out + (rowbase + j) * DOUT + col);
        }
    }
}

// ---------------------------------------------------------------------------
extern "C" void kernel_launch(void* const* d_in, const int* in_sizes, int n_in,
                              void* d_out, int out_size, void* d_ws, size_t ws_size,
                              hipStream_t stream) {
    (void)in_sizes; (void)n_in; (void)out_size; (void)ws_size;
    const float* x    = (const float*)d_in[0];
    const float* vg   = (const float*)d_in[1];
    const float* ev   = (const float*)d_in[2];
    const float* W1   = (const float*)d_in[5];
    const float* b1   = (const float*)d_in[6];
    const float* g1   = (const float*)d_in[7];
    const float* be1  = (const float*)d_in[8];
    const float* W2   = (const float*)d_in[9];
    const float* b2   = (const float*)d_in[10];
    const float* g2   = (const float*)d_in[11];
    const float* be2  = (const float*)d_in[12];
    const float* Wqkv = (const float*)d_in[13];
    const float* bqkv = (const float*)d_in[14];
    const float* Wo   = (const float*)d_in[15];
    const float* bo   = (const float*)d_in[16];
    const float* Wf1  = (const float*)d_in[17];
    const float* bf1  = (const float*)d_in[18];
    const float* Wf2  = (const float*)d_in[19];
    const float* bf2  = (const float*)d_in[20];
    const float* Wp   = (const float*)d_in[21];
    const float* bp   = (const float*)d_in[22];
    const float* gp   = (const float*)d_in[23];
    const float* bep  = (const float*)d_in[24];

    float* outf    = (float*)d_out;
    float* ws      = (float*)d_ws;
    float* filters = ws;                              // 2048 floats
    unsigned short* Gt = (unsigned short*)(ws + 4096);// B*512*32 bf16 (2 MB)
    float* xfp     = outf;                            // scratch 33.5 MB @ 0
    float* F       = outf + 16777216;                 // scratch 4 MB @ 64 MB
                                                      // (both overwritten by k4)

    hipLaunchKernelGGL(k1_filters, dim3(B), dim3(1024), 0, stream,
                       ev, W1, b1, g1, be1, W2, b2, g2, be2,
                       Wqkv, bqkv, Wo, bo, Wf1, bf1, Wf2, bf2, filters);
    hipLaunchKernelGGL(k2_xfreq_partial, dim3(B * 16), dim3(256), 0, stream,
                       x, vg, xfp);
    hipLaunchKernelGGL(k2b_combine, dim3(1024), dim3(256), 0, stream,
                       xfp, filters, F);
    hipLaunchKernelGGL(k3_G, dim3(32 * 8), dim3(256), 0, stream,
                       F, Wp, Gt);
    hipLaunchKernelGGL(k4_out, dim3(B * 16), dim3(256), 0, stream,
                       vg, Gt, bp, gp, bep, outf);
}

// Round 15
// 129.728 us; speedup vs baseline: 1.0153x; 1.0153x over previous
//
#include <hip/hip_runtime.h>
#include <math.h>

#define B    64
#define NPG  1024
#define KEIG 32
#define DIN  512
#define DOUT 512
#define NPART 8   // k2 n-chunk partials

typedef float  f32x4  __attribute__((ext_vector_type(4)));
typedef short  bf16x8 __attribute__((ext_vector_type(8)));

__device__ __forceinline__ unsigned short f2bf(float x) {
    union { float f; unsigned int u; } v; v.f = x;
    unsigned int r = v.u + 0x7FFFu + ((v.u >> 16) & 1u);   // round-nearest-even
    return (unsigned short)(r >> 16);
}

__device__ __forceinline__ float rsum32(float v) {
    v += __shfl_xor(v, 1, 32);
    v += __shfl_xor(v, 2, 32);
    v += __shfl_xor(v, 4, 32);
    v += __shfl_xor(v, 8, 32);
    v += __shfl_xor(v, 16, 32);
    return v;
}
__device__ __forceinline__ float rmax32(float v) {
    v = fmaxf(v, __shfl_xor(v, 1, 32));
    v = fmaxf(v, __shfl_xor(v, 2, 32));
    v = fmaxf(v, __shfl_xor(v, 4, 32));
    v = fmaxf(v, __shfl_xor(v, 8, 32));
    v = fmaxf(v, __shfl_xor(v, 16, 32));
    return v;
}

// ---------------------------------------------------------------------------
// Kernel 1: feature-parallel encoder + MHSA + filter head. (~8us, unchanged)
// ---------------------------------------------------------------------------
__global__ __launch_bounds__(1024) void k1_filters(
    const float* __restrict__ eigenvalues,
    const float* __restrict__ W1,  const float* __restrict__ b1,
    const float* __restrict__ g1,  const float* __restrict__ be1,
    const float* __restrict__ W2,  const float* __restrict__ b2,
    const float* __restrict__ g2,  const float* __restrict__ be2,
    const float* __restrict__ Wqkv,const float* __restrict__ bqkv,
    const float* __restrict__ Wo,  const float* __restrict__ bo,
    const float* __restrict__ Wf1, const float* __restrict__ bf1,
    const float* __restrict__ Wf2, const float* __restrict__ bf2,
    float* __restrict__ filters)
{
    __shared__ float wts[224][33];
    __shared__ float hA[KEIG][33];
    __shared__ float hB[KEIG][33];
    __shared__ float qkv[KEIG][97];
    __shared__ float attn[4 * 1064];

    const int t = threadIdx.x;
    const int k = t >> 5;
    const int j = t & 31;
    const int b = blockIdx.x;

    {
        const int row = t >> 5, i = t & 31;
        wts[row][i]       = W2[t];
        wts[32 + row][i]  = Wqkv[t];
        wts[64 + row][i]  = Wqkv[1024 + t];
        wts[96 + row][i]  = Wqkv[2048 + t];
        wts[128 + row][i] = Wo[t];
        wts[160 + row][i] = Wf1[t];
        wts[192 + row][i] = Wf1[1024 + t];
    }

    const float ev = eigenvalues[b * KEIG + k];
    float h1 = ev * W1[j] + b1[j];
    {
        float m = rsum32(h1) * (1.f / 32.f);
        float d = h1 - m;
        float q = rsum32(d * d);
        float r = rsqrtf(q * (1.f / 32.f) + 1e-5f);
        h1 = fmaxf(d * r * g1[j] + be1[j], 0.f);
    }
    hA[k][j] = h1;
    __syncthreads();

    {
        float a = b2[j];
        #pragma unroll
        for (int i = 0; i < 32; ++i) a += hA[k][i] * wts[j][i];
        float m = rsum32(a) * (1.f / 32.f);
        float d = a - m;
        float q = rsum32(d * d);
        float r = rsqrtf(q * (1.f / 32.f) + 1e-5f);
        hB[k][j] = d * r * g2[j] + be2[j];
    }
    __syncthreads();

    {
        float aq = bqkv[j], ak = bqkv[32 + j], av = bqkv[64 + j];
        #pragma unroll
        for (int i = 0; i < 32; ++i) {
            float hv = hB[k][i];
            aq += hv * wts[32 + j][i];
            ak += hv * wts[64 + j][i];
            av += hv * wts[96 + j][i];
        }
        qkv[k][j]      = aq;
        qkv[k][32 + j] = ak;
        qkv[k][64 + j] = av;
    }
    __syncthreads();

    {
        const float inv = 0.35355339059327373f;
        float sc[4];
        #pragma unroll
        for (int hh = 0; hh < 4; ++hh) {
            float s = 0.f;
            #pragma unroll
            for (int d2 = 0; d2 < 8; ++d2)
                s += qkv[k][hh * 8 + d2] * qkv[j][32 + hh * 8 + d2];
            sc[hh] = s * inv;
        }
        #pragma unroll
        for (int hh = 0; hh < 4; ++hh) {
            float mx  = rmax32(sc[hh]);
            float e   = __expf(sc[hh] - mx);
            float den = rsum32(e);
            attn[hh * 1064 + k * 33 + j] = e / den;
        }
    }
    __syncthreads();

    {
        const int hh = j >> 3;
        float c = 0.f;
        #pragma unroll
        for (int k2 = 0; k2 < 32; ++k2)
            c += attn[hh * 1064 + k * 33 + k2] * qkv[k2][64 + j];
        hA[k][j] = c;
    }
    __syncthreads();

    {
        float o = bo[j];
        #pragma unroll
        for (int i = 0; i < 32; ++i) o += hA[k][i] * wts[128 + j][i];
        hB[k][j] = o;
    }
    __syncthreads();

    {
        float r0 = bf1[j], r1 = bf1[32 + j];
        #pragma unroll
        for (int i = 0; i < 32; ++i) {
            float ov = hB[k][i];
            r0 += ov * wts[160 + j][i];
            r1 += ov * wts[192 + j][i];
        }
        float fp = fmaxf(r0, 0.f) * Wf2[j] + fmaxf(r1, 0.f) * Wf2[32 + j];
        fp = rsum32(fp);
        if (j == 0) filters[b * KEIG + k] = tanhf(fp + bf2[0]);
    }
}

// ---------------------------------------------------------------------------
// Kernel 2: xfp[nc][b][k][d] = sum_{n in 128-row chunk} vg[n,k]*x[n,d]
// (~30us; near its 176MB traffic roofline, unchanged)
// ---------------------------------------------------------------------------
__global__ __launch_bounds__(256) void k2_xfreq_partial(
    const float* __restrict__ x, const float* __restrict__ eigvec,
    float* __restrict__ xfp)
{
    __shared__ float vtile[128][32];
    const int t  = threadIdx.x;
    const int b  = blockIdx.x >> 4;
    const int nc = (blockIdx.x >> 1) & 7;
    const int dh = blockIdx.x & 1;
    const int kq = t >> 6;
    const int ds = t & 63;
    const int d  = dh * 256 + ds * 4;
    const int n0 = nc * 128;

    const float* vb = eigvec + ((size_t)(b * NPG + n0)) * KEIG;
    #pragma unroll
    for (int e = 0; e < 16; ++e) {
        int idx = t + e * 256;
        ((float*)vtile)[idx] = vb[idx];
    }
    __syncthreads();

    float4 acc[8];
    #pragma unroll
    for (int i = 0; i < 8; ++i) acc[i] = make_float4(0.f, 0.f, 0.f, 0.f);

    const float* xb = x + ((size_t)(b * NPG + n0)) * DIN + d;
    #pragma unroll 4
    for (int n = 0; n < 128; ++n) {
        float4 xv = *(const float4*)(xb + (size_t)n * DIN);
        const float4* vp = (const float4*)&vtile[n][kq * 8];
        float4 v0 = vp[0], v1 = vp[1];
        acc[0].x += v0.x * xv.x; acc[0].y += v0.x * xv.y; acc[0].z += v0.x * xv.z; acc[0].w += v0.x * xv.w;
        acc[1].x += v0.y * xv.x; acc[1].y += v0.y * xv.y; acc[1].z += v0.y * xv.z; acc[1].w += v0.y * xv.w;
        acc[2].x += v0.z * xv.x; acc[2].y += v0.z * xv.y; acc[2].z += v0.z * xv.z; acc[2].w += v0.z * xv.w;
        acc[3].x += v0.w * xv.x; acc[3].y += v0.w * xv.y; acc[3].z += v0.w * xv.z; acc[3].w += v0.w * xv.w;
        acc[4].x += v1.x * xv.x; acc[4].y += v1.x * xv.y; acc[4].z += v1.x * xv.z; acc[4].w += v1.x * xv.w;
        acc[5].x += v1.y * xv.x; acc[5].y += v1.y * xv.y; acc[5].z += v1.y * xv.z; acc[5].w += v1.y * xv.w;
        acc[6].x += v1.z * xv.x; acc[6].y += v1.z * xv.y; acc[6].z += v1.z * xv.z; acc[6].w += v1.z * xv.w;
        acc[7].x += v1.w * xv.x; acc[7].y += v1.w * xv.y; acc[7].z += v1.w * xv.z; acc[7].w += v1.w * xv.w;
    }

    #pragma unroll
    for (int kk = 0; kk < 8; ++kk) {
        int kg = kq * 8 + kk;
        *(float4*)(xfp + (((size_t)nc * B + b) * KEIG + kg) * DIN + d) = acc[kk];
    }
}

// ---------------------------------------------------------------------------
// Kernel 2b: F[m][d] = filters[m] * sum_nc xfp[nc][m][d].  (~7us, unchanged)
// ---------------------------------------------------------------------------
__global__ __launch_bounds__(256) void k2b_combine(
    const float* __restrict__ xfp, const float* __restrict__ filters,
    float* __restrict__ F)
{
    const int t = threadIdx.x;
    const int m = blockIdx.x * 2 + (t >> 7);
    const int dp = (t & 127) * 4;

    const float* base = xfp + (size_t)m * DIN + dp;
    float4 s = *(const float4*)base;
    #pragma unroll
    for (int q = 1; q < NPART; ++q) {
        float4 sq = *(const float4*)(base + (size_t)q * (B * KEIG * DIN));
        s.x += sq.x; s.y += sq.y; s.z += sq.z; s.w += sq.w;
    }
    const float f = filters[m];
    float4 o = make_float4(s.x * f, s.y * f, s.z * f, s.w * f);
    *(float4*)(F + (size_t)m * DIN + dp) = o;
}

// ---------------------------------------------------------------------------
// Kernel 3: GEMM G[m][o] = sum_d F[m][d]*Wp[o][d], emitting G transposed in
// bf16: Gt[b][o][k] (2 MB). ~15us. (unchanged from R13)
// ---------------------------------------------------------------------------
__global__ __launch_bounds__(256) void k3_G(
    const float* __restrict__ F, const float* __restrict__ Wp,
    unsigned short* __restrict__ Gt)
{
    __shared__ float a_lds[64][65];
    __shared__ float b_lds[64][65];

    const int t   = threadIdx.x;
    const int mt  = blockIdx.x >> 3;
    const int ot  = blockIdx.x & 7;
    const int m0  = mt * 64;
    const int o0  = ot * 64;
    const int tr  = t >> 4;
    const int tc  = t & 15;
    const int col4 = tc * 4;

    float acc[4][4] = {{0.f}};

    for (int d0 = 0; d0 < DIN; d0 += 64) {
        __syncthreads();
        #pragma unroll
        for (int p = 0; p < 4; ++p) {
            int r = p * 16 + tr;
            float4 s = *(const float4*)(F + (size_t)(m0 + r) * DIN + d0 + col4);
            a_lds[r][col4 + 0] = s.x;
            a_lds[r][col4 + 1] = s.y;
            a_lds[r][col4 + 2] = s.z;
            a_lds[r][col4 + 3] = s.w;
        }
        #pragma unroll
        for (int p = 0; p < 4; ++p) {
            int r = p * 16 + tr;
            float4 w = *(const float4*)(Wp + (size_t)(o0 + r) * DIN + d0 + col4);
            b_lds[r][col4 + 0] = w.x;
            b_lds[r][col4 + 1] = w.y;
            b_lds[r][col4 + 2] = w.z;
            b_lds[r][col4 + 3] = w.w;
        }
        __syncthreads();
        #pragma unroll 4
        for (int dd = 0; dd < 64; ++dd) {
            float a0 = a_lds[tr * 4 + 0][dd];
            float a1 = a_lds[tr * 4 + 1][dd];
            float a2 = a_lds[tr * 4 + 2][dd];
            float a3 = a_lds[tr * 4 + 3][dd];
            float b0 = b_lds[tc * 4 + 0][dd];
            float b1 = b_lds[tc * 4 + 1][dd];
            float b2 = b_lds[tc * 4 + 2][dd];
            float b3 = b_lds[tc * 4 + 3][dd];
            acc[0][0] += a0 * b0; acc[0][1] += a0 * b1; acc[0][2] += a0 * b2; acc[0][3] += a0 * b3;
            acc[1][0] += a1 * b0; acc[1][1] += a1 * b1; acc[1][2] += a1 * b2; acc[1][3] += a1 * b3;
            acc[2][0] += a2 * b0; acc[2][1] += a2 * b1; acc[2][2] += a2 * b2; acc[2][3] += a2 * b3;
            acc[3][0] += a3 * b0; acc[3][1] += a3 * b1; acc[3][2] += a3 * b2; acc[3][3] += a3 * b3;
        }
    }
    #pragma unroll
    for (int i = 0; i < 4; ++i) {
        int m  = m0 + tr * 4 + i;
        int bb = m >> 5, kk = m & 31;
        #pragma unroll
        for (int j = 0; j < 4; ++j) {
            int o = o0 + tc * 4 + j;
            Gt[((size_t)bb * DOUT + o) * KEIG + kk] = f2bf(acc[i][j]);
        }
    }
}

// ---------------------------------------------------------------------------
// Kernel 4 (v12 — 1-wave blocks, zero LDS, zero barriers):
// out[n,:] = LN( vg[n,:] @ G[b] + bp ) * gp + bep   via MFMA (v11 datapath,
// verified absmax 7.8e-3). grid = B*64 = 4096 blocks x 64 thr: each WAVE
// owns 16 rows x 512 cols independently. All nine prior variants shared a
// stage->barrier->compute->128KB-store-burst structure at 2-3 blocks/CU
// (4 serialized generations/CU ~ 72us regardless of compute/LDS/occupancy
// knobs). Here: B-frags read directly from L2-resident Gt (32KB/wave), no
// staging, no barrier -> ~8 desynchronized waves/CU stream stores
// continuously (the fill kernel's 7 TB/s profile).
// ---------------------------------------------------------------------------
__global__ __launch_bounds__(64) void k4_out(
    const float* __restrict__ eigvec, const unsigned short* __restrict__ Gt,
    const float* __restrict__ bp, const float* __restrict__ gp,
    const float* __restrict__ bep, float* __restrict__ out)
{
    const int wave = blockIdx.x;
    const int b    = wave >> 6;          // batch
    const int n0   = (wave & 63) * 16;   // this wave's 16 rows

    const int l  = threadIdx.x;
    const int cl = l & 15;               // col-in-tile / A-row lane
    const int g  = l >> 4;               // lane group 0..3
    const int kb = g * 8;                // k-slice

    // A fragment: vg[b*NPG + n0 + cl][kb..kb+7] -> 8 bf16 (RNE)
    bf16x8 afrag;
    {
        const float* ar = eigvec + ((size_t)(b * NPG + n0 + cl)) * KEIG + kb;
        float4 a0 = *(const float4*)(ar);
        float4 a1 = *(const float4*)(ar + 4);
        afrag[0] = (short)f2bf(a0.x); afrag[1] = (short)f2bf(a0.y);
        afrag[2] = (short)f2bf(a0.z); afrag[3] = (short)f2bf(a0.w);
        afrag[4] = (short)f2bf(a1.x); afrag[5] = (short)f2bf(a1.y);
        afrag[6] = (short)f2bf(a1.z); afrag[7] = (short)f2bf(a1.w);
    }

    // 32 col-tiles: B-frag straight from L2-resident Gt[b] (no LDS)
    const unsigned short* gb = Gt + (size_t)b * (DOUT * KEIG);
    f32x4 acc[32];
    #pragma unroll
    for (int ct = 0; ct < 32; ++ct) acc[ct] = (f32x4){0.f, 0.f, 0.f, 0.f};

    #pragma unroll
    for (int ct = 0; ct < 32; ++ct) {
        bf16x8 bfrag = *(const bf16x8*)(gb + (size_t)(ct * 16 + cl) * KEIG + kb);
        acc[ct] = __builtin_amdgcn_mfma_f32_16x16x32_bf16(afrag, bfrag, acc[ct], 0, 0, 0);
    }

    // LN stats: lane holds rows g*4+j (j=0..3), cols {ct*16+cl}
    float s[4] = {0.f, 0.f, 0.f, 0.f}, q[4] = {0.f, 0.f, 0.f, 0.f};
    #pragma unroll
    for (int ct = 0; ct < 32; ++ct) {
        float bpc = bp[ct * 16 + cl];
        #pragma unroll
        for (int j = 0; j < 4; ++j) {
            float v = acc[ct][j] + bpc;
            s[j] += v; q[j] += v * v;
        }
    }
    #pragma unroll
    for (int off = 1; off < 16; off <<= 1) {
        #pragma unroll
        for (int j = 0; j < 4; ++j) {
            s[j] += __shfl_xor(s[j], off, 16);
            q[j] += __shfl_xor(q[j], off, 16);
        }
    }
    float mh[4], rs[4];
    #pragma unroll
    for (int j = 0; j < 4; ++j) {
        mh[j] = s[j] * (1.f / 512.f);
        rs[j] = rsqrtf(q[j] * (1.f / 512.f) - mh[j] * mh[j] + 1e-5f);
    }

    // stores: 4 rows x 32 col-tiles, 64B per 16-lane group, NT scalar
    const size_t rowbase = (size_t)b * NPG + n0 + g * 4;
    #pragma unroll
    for (int ct = 0; ct < 32; ++ct) {
        int col = ct * 16 + cl;
        float bpc = bp[col];
        float gpc = gp[col];
        float bec = bep[col];
        #pragma unroll
        for (int j = 0; j < 4; ++j) {
            float v = (acc[ct][j] + bpc - mh[j]) * rs[j] * gpc + bec;
            __builtin_nontemporal_store(v, out + (rowbase + j) * DOUT + col);
        }
    }
}

// ---------------------------------------------------------------------------
extern "C" void kernel_launch(void* const* d_in, const int* in_sizes, int n_in,
                              void* d_out, int out_size, void* d_ws, size_t ws_size,
                              hipStream_t stream) {
    (void)in_sizes; (void)n_in; (void)out_size; (void)ws_size;
    const float* x    = (const float*)d_in[0];
    const float* vg   = (const float*)d_in[1];
    const float* ev   = (const float*)d_in[2];
    const float* W1   = (const float*)d_in[5];
    const float* b1   = (const float*)d_in[6];
    const float* g1   = (const float*)d_in[7];
    const float* be1  = (const float*)d_in[8];
    const float* W2   = (const float*)d_in[9];
    const float* b2   = (const float*)d_in[10];
    const float* g2   = (const float*)d_in[11];
    const float* be2  = (const float*)d_in[12];
    const float* Wqkv = (const float*)d_in[13];
    const float* bqkv = (const float*)d_in[14];
    const float* Wo   = (const float*)d_in[15];
    const float* bo   = (const float*)d_in[16];
    const float* Wf1  = (const float*)d_in[17];
    const float* bf1  = (const float*)d_in[18];
    const float* Wf2  = (const float*)d_in[19];
    const float* bf2  = (const float*)d_in[20];
    const float* Wp   = (const float*)d_in[21];
    const float* bp   = (const float*)d_in[22];
    const float* gp   = (const float*)d_in[23];
    const float* bep  = (const float*)d_in[24];

    float* outf    = (float*)d_out;
    float* ws      = (float*)d_ws;
    float* filters = ws;                              // 2048 floats
    unsigned short* Gt = (unsigned short*)(ws + 4096);// B*512*32 bf16 (2 MB)
    float* xfp     = outf;                            // scratch 33.5 MB @ 0
    float* F       = outf + 16777216;                 // scratch 4 MB @ 64 MB
                                                      // (both overwritten by k4)

    hipLaunchKernelGGL(k1_filters, dim3(B), dim3(1024), 0, stream,
                       ev, W1, b1, g1, be1, W2, b2, g2, be2,
                       Wqkv, bqkv, Wo, bo, Wf1, bf1, Wf2, bf2, filters);
    hipLaunchKernelGGL(k2_xfreq_partial, dim3(B * 16), dim3(256), 0, stream,
                       x, vg, xfp);
    hipLaunchKernelGGL(k2b_combine, dim3(1024), dim3(256), 0, stream,
                       xfp, filters, F);
    hipLaunchKernelGGL(k3_G, dim3(32 * 8), dim3(256), 0, stream,
                       F, Wp, Gt);
    hipLaunchKernelGGL(k4_out, dim3(B * 64), dim3(64), 0, stream,
                       vg, Gt, bp, gp, bep, outf);
}